// Round 14
// baseline (69.304 us; speedup 1.0000x reference)
//
#include <hip/hip_runtime.h>

typedef unsigned short u16;
typedef unsigned int   u32;
typedef u16   u16x8 __attribute__((ext_vector_type(8)));
typedef float f32x4 __attribute__((ext_vector_type(4)));
typedef __bf16 bf16x8 __attribute__((ext_vector_type(8)));
typedef u32   u32x2 __attribute__((ext_vector_type(2)));
typedef u32   u32x4 __attribute__((ext_vector_type(4)));

#define QSCALE  0.18033688011112f     // 0.125 * log2(e): scores in exp2 units
#define BM_OPEN  -28.8539008177793f   // -20 * log2(e)
#define BM_MASK  -14455.8043097f      // -(10000+20) * log2(e)

__device__ __forceinline__ u16 f2bf(float x){
  __bf16 h = (__bf16)x;
  return __builtin_bit_cast(u16, h);
}
__device__ __forceinline__ f32x4 mfma16x16x32(u16x8 a, u16x8 b, f32x4 c){
  return __builtin_amdgcn_mfma_f32_16x16x32_bf16(
      __builtin_bit_cast(bf16x8, a), __builtin_bit_cast(bf16x8, b), c, 0, 0, 0);
}
__device__ __forceinline__ void gld16(const void* g, void* l){
  __builtin_amdgcn_global_load_lds(
      (const __attribute__((address_space(1))) u32*)g,
      (__attribute__((address_space(3))) u32*)l, 16, 0, 0);
}

// ===================== layout =====================
// Per (b,h,kt) tile: 8192 u16 = [K 4096 | V 4096], 16384 B.
//  K: K[key][d] bf16. Row=key, stride 64 u16 (128 B). chunk c at c ^ (key&7).
//  V: V^T[d][s] u32 (s,s+1)-pairs. Row=d, 32 u32. chunk c at c ^ (d&7).

// ===================== pre-pass: f32 KV -> swizzled bf16 tile image ==========
__global__ __launch_bounds__(256, 4)
void prepass(const float* __restrict__ KV, const int* __restrict__ MASK,
             u16* __restrict__ IMG, float* __restrict__ BIASM)
{
  const int tid = threadIdx.x;
  const int bid = blockIdx.x;        // ((b*16+h)*32 + kt)
  const int kt = bid & 31;
  const int h  = (bid >> 5) & 15;
  const int b  = bid >> 9;
  const int kb = kt*64;
  const size_t kv_b = (size_t)b*(2048u*2048u);
  u16* tile = IMG + (size_t)bid * 8192;

  {
    const int skey = tid >> 2, scp = tid & 3;
    const float* kp = KV + kv_b + (size_t)(kb + skey)*2048 + h*64 + 16*scp;
    f32x4 f0 = *(const f32x4*)(kp);
    f32x4 f1 = *(const f32x4*)(kp + 4);
    f32x4 f2 = *(const f32x4*)(kp + 8);
    f32x4 f3 = *(const f32x4*)(kp + 12);
    u16x8 c0, c1;
    #pragma unroll
    for (int e = 0; e < 4; ++e){
      c0[e] = f2bf(f0[e]); c0[e+4] = f2bf(f1[e]);
      c1[e] = f2bf(f2[e]); c1[e+4] = f2bf(f3[e]);
    }
    const int idx0 = skey*64 + (((2*scp) ^ (skey & 7)) << 3);
    *(u16x8*)&tile[idx0]     = c0;
    *(u16x8*)&tile[idx0 ^ 8] = c1;
  }
  {
    const int sdb = tid & 7, ssp = tid >> 3;
    const float* vp = KV + kv_b + (size_t)(kb + 2*ssp)*2048 + 1024 + h*64 + 8*sdb;
    f32x4 r0a = *(const f32x4*)(vp);
    f32x4 r0b = *(const f32x4*)(vp + 4);
    f32x4 r1a = *(const f32x4*)(vp + 2048);
    f32x4 r1b = *(const f32x4*)(vp + 2048 + 4);
    u32* vimg = (u32*)(tile + 4096);
    const int wc = ssp >> 2, wi = ssp & 3;
    #pragma unroll
    for (int j = 0; j < 4; ++j){
      const int d0 = 8*sdb + j;
      const int d1 = d0 + 4;
      vimg[d0*32 + ((wc ^ (d0 & 7)) << 2) + wi] = (u32)f2bf(r0a[j]) | ((u32)f2bf(r1a[j]) << 16);
      vimg[d1*32 + ((wc ^ (d1 & 7)) << 2) + wi] = (u32)f2bf(r0b[j]) | ((u32)f2bf(r1b[j]) << 16);
    }
  }
  if (h == 0 && tid < 64){
    const int s = kb + tid;
    BIASM[b*2048 + s] = MASK[b*2048 + s] ? BM_OPEN : BM_MASK;
  }
}

// ===================== main: MFMA flash attention, fixed-shift softmax =======
// Grid 512. Block = 8 waves x 16 q-rows = 128 rows (512 threads).
// 2 blocks/CU = 16 waves/CU = 4 waves/SIMD.
// PRE=1: triple-buffered DMA, depth-2, counted vmcnt + raw s_barrier.
// PRE=0: fallback, double-buffered reg staging with __syncthreads.
template<int PRE>
__global__ __launch_bounds__(512, 4)
void attn_main(const float* __restrict__ Q, const float* __restrict__ KV,
               const int* __restrict__ MASK, const u16* __restrict__ IMG,
               const float* __restrict__ BIASM, float* __restrict__ OUT)
{
  __shared__ __align__(16) u16 KVbuf[3][8192];   // 48 KB (PRE=0 uses [0],[1])
  __shared__ __align__(16) u32 Pw[8][16*36];     // per-wave P, stride-36 (18 KB)

  const int tid  = threadIdx.x;
  const int w    = tid >> 6;
  const int lane = tid & 63;
  const int lg   = (lane >> 4) & 3;
  const int ln   = lane & 15;

  const int bid0 = blockIdx.x;
  const int bid  = (bid0 & 7)*64 + (bid0 >> 3);   // XCD swizzle (bijective 8x64)
  const int qt  = bid & 15;
  const int h   = (bid >> 4) & 15;
  const int b   = bid >> 8;

  const int qbase = qt*128 + w*16;
  const size_t q_b  = (size_t)b * (2048u*1024u);
  const size_t kv_b = (size_t)b * (2048u*2048u);

  const int lnoff = ln*64;
  const int ck0   = ((lg ^ (ln & 7)) << 3);
  const int ck1   = ck0 ^ 32;

  // ---- Q fragment (16 q-rows per wave) ----
  u16x8 Qf[2];
  {
    const int qrow = qbase + ln;
    const float* qp = Q + q_b + (size_t)qrow*1024 + h*64 + 8*lg;
    #pragma unroll
    for (int kc = 0; kc < 2; ++kc){
      f32x4 a = *(const f32x4*)(qp + 32*kc);
      f32x4 c = *(const f32x4*)(qp + 32*kc + 4);
      u16x8 v;
      #pragma unroll
      for (int e = 0; e < 4; ++e){
        v[e]     = f2bf(a[e] * QSCALE);
        v[e + 4] = f2bf(c[e] * QSCALE);
      }
      Qf[kc] = v;
    }
  }

  f32x4 Oacc[4];
  #pragma unroll
  for (int dt = 0; dt < 4; ++dt) Oacc[dt] = f32x4{0.f,0.f,0.f,0.f};
  float lrun = 0.f;

  // staging constants
  const char* img0 = (const char*)IMG + (size_t)((b*16 + h)*32) * 16384;
  const int so = tid*16;                        // PRE=1: 2 x 16B per thread
  const int skey = tid >> 3, scp7 = tid & 7;    // PRE=0 K: 1 chunk per thread
  const int sdb = tid & 7, spr = (tid >> 3) & 31, vh = tid >> 8;  // PRE=0 V
  const float* kp0 = KV + kv_b + (size_t)skey*2048 + h*64 + 8*scp7;
  const float* vp0 = KV + kv_b + (size_t)(2*spr)*2048 + 1024 + h*64 + 8*sdb + 4*vh;
  f32x4 kfa, kfb, vfa, vfc;                     // PRE=0 staging regs

#define STAGE_ISSUE(T, DST) do{                                               \
    const char* g_ = img0 + (size_t)(T)*16384;                                \
    char* l_ = (char*)(DST);                                                  \
    gld16(g_+so,        l_+so);                                               \
    gld16(g_+so+8192,   l_+so+8192);                                          \
  }while(0)

#define STAGE_REG(T) do{                                                      \
    const float* kp_ = kp0 + (size_t)(T)*64*2048;                             \
    kfa = *(const f32x4*)(kp_); kfb = *(const f32x4*)(kp_+4);                 \
    const float* vp_ = vp0 + (size_t)(T)*64*2048;                             \
    vfa = *(const f32x4*)(vp_); vfc = *(const f32x4*)(vp_+2048);              \
  }while(0)

#define STAGE_WRITE(DST) do{                                                  \
    u16x8 c0_;                                                                \
    _Pragma("unroll") for (int e_=0; e_<4; ++e_){                             \
      c0_[e_] = f2bf(kfa[e_]); c0_[e_+4] = f2bf(kfb[e_]); }                   \
    *(u16x8*)&(DST)[skey*64 + ((scp7 ^ (skey & 7)) << 3)] = c0_;              \
    u32* vimg_ = (u32*)((DST)+4096);                                          \
    const int wc_ = spr >> 2, wi_ = spr & 3;                                  \
    _Pragma("unroll") for (int j_=0; j_<4; ++j_){                             \
      const int d_ = 8*sdb + 4*vh + j_;                                       \
      vimg_[d_*32 + ((wc_ ^ (d_&7)) << 2) + wi_] =                            \
          (u32)f2bf(vfa[j_]) | ((u32)f2bf(vfc[j_]) << 16);                    \
    }                                                                         \
  }while(0)

#define COMPUTE(T, CUR) do{                                                   \
    const u16* Kb_ = (CUR);                                                   \
    const u16* Vb_ = (CUR) + 4096;                                            \
    f32x4 bv[4];                                                              \
    _Pragma("unroll") for (int ct = 0; ct < 4; ++ct){                         \
      if constexpr (PRE){                                                     \
        bv[ct] = *(const f32x4*)(BIASM + b*2048 + (T)*64 + 16*ct + 4*lg);     \
      } else {                                                                \
        const int4 mv = *(const int4*)(MASK + b*2048 + (T)*64 + 16*ct + 4*lg);\
        bv[ct][0] = mv.x ? BM_OPEN : BM_MASK;                                 \
        bv[ct][1] = mv.y ? BM_OPEN : BM_MASK;                                 \
        bv[ct][2] = mv.z ? BM_OPEN : BM_MASK;                                 \
        bv[ct][3] = mv.w ? BM_OPEN : BM_MASK;                                 \
      }                                                                       \
    }                                                                         \
    f32x4 S[4];                                                               \
    _Pragma("unroll") for (int ct = 0; ct < 4; ++ct)                          \
      S[ct] = f32x4{0.f,0.f,0.f,0.f};                                         \
    __builtin_amdgcn_s_setprio(1);                                            \
    _Pragma("unroll") for (int ct = 0; ct < 4; ++ct){                         \
      const int rb = ct*1024 + lnoff;                                         \
      u16x8 k0 = *(const u16x8*)&Kb_[rb + ck0];                               \
      u16x8 k1 = *(const u16x8*)&Kb_[rb + ck1];                               \
      S[ct] = mfma16x16x32(k0, Qf[0], S[ct]);                                 \
      S[ct] = mfma16x16x32(k1, Qf[1], S[ct]);                                 \
    }                                                                         \
    __builtin_amdgcn_s_setprio(0);                                            \
    float ps = 0.f;                                                           \
    _Pragma("unroll") for (int ct = 0; ct < 4; ++ct){                         \
      _Pragma("unroll") for (int r = 0; r < 4; ++r){                          \
        const float p = __builtin_amdgcn_exp2f(S[ct][r] + bv[ct][r]);         \
        S[ct][r] = p;                                                         \
        ps += p;                                                              \
      }                                                                       \
    }                                                                         \
    lrun += ps;                                                               \
    _Pragma("unroll") for (int ct = 0; ct < 4; ++ct){                         \
      u32x2 pw;                                                               \
      pw[0] = (u32)f2bf(S[ct][0]) | ((u32)f2bf(S[ct][1]) << 16);              \
      pw[1] = (u32)f2bf(S[ct][2]) | ((u32)f2bf(S[ct][3]) << 16);              \
      *(u32x2*)&Pw[w][ln*36 + 8*ct + 2*lg] = pw;                              \
    }                                                                         \
    asm volatile("" ::: "memory");                                            \
    u16x8 Pf[2];                                                              \
    _Pragma("unroll") for (int sc = 0; sc < 2; ++sc){                         \
      u32x4 pr = *(const u32x4*)&Pw[w][ln*36 + 4*lg + 16*sc];                 \
      Pf[sc] = __builtin_bit_cast(u16x8, pr);                                 \
    }                                                                         \
    __builtin_amdgcn_s_setprio(1);                                            \
    _Pragma("unroll") for (int dt = 0; dt < 4; ++dt){                         \
      const int rb = dt*1024 + lnoff;                                         \
      u16x8 v0 = *(const u16x8*)&Vb_[rb + ck0];                               \
      u16x8 v1 = *(const u16x8*)&Vb_[rb + ck1];                               \
      Oacc[dt] = mfma16x16x32(v0, Pf[0], Oacc[dt]);                           \
      Oacc[dt] = mfma16x16x32(v1, Pf[1], Oacc[dt]);                           \
    }                                                                         \
    __builtin_amdgcn_s_setprio(0);                                            \
  }while(0)

#define SEAM(N) do{                                                           \
    __builtin_amdgcn_sched_barrier(0);                                        \
    asm volatile("s_waitcnt vmcnt(%0)" :: "i"(N) : "memory");                 \
    __builtin_amdgcn_sched_barrier(0);                                        \
    __builtin_amdgcn_s_barrier();                                             \
  }while(0)

#define PITER(T, CUR, FREE) do{                                               \
    if ((T) + 2 <= 31) STAGE_ISSUE((T)+2, FREE);                              \
    COMPUTE(T, CUR);                                                          \
    SEAM(2);                                                                  \
  }while(0)

  if constexpr (PRE){
    u16* b0 = &KVbuf[0][0];
    u16* b1 = &KVbuf[1][0];
    u16* b2 = &KVbuf[2][0];
    STAGE_ISSUE(0, b0);
    STAGE_ISSUE(1, b1);
    SEAM(2);
    for (int u = 0; u < 10; ++u){
      PITER(3*u    , b0, b2);
      PITER(3*u + 1, b1, b0);
      PITER(3*u + 2, b2, b1);
    }
    COMPUTE(30, b0);
    SEAM(0);
    COMPUTE(31, b1);
  } else {
    STAGE_REG(0);
    STAGE_WRITE(&KVbuf[0][0]);
    __syncthreads();
    for (int t = 0; t < 32; ++t){
      if (t < 31) STAGE_REG(t+1);
      COMPUTE(t, &KVbuf[t & 1][0]);
      if (t < 31){
        STAGE_WRITE(&KVbuf[(t+1) & 1][0]);
        __syncthreads();
      }
    }
  }

  // ---- epilogue: reduce partial l, normalize, store f32 ----
  {
    float l_ = lrun;
    l_ += __shfl_xor(l_, 16, 64);
    l_ += __shfl_xor(l_, 32, 64);
    const float inv = 1.f / l_;
    const int qrow = qbase + ln;
    float* op = OUT + q_b + (size_t)qrow*1024 + h*64;
    #pragma unroll
    for (int dt = 0; dt < 4; ++dt){
      f32x4 ov;
      ov[0] = Oacc[dt][0] * inv;
      ov[1] = Oacc[dt][1] * inv;
      ov[2] = Oacc[dt][2] * inv;
      ov[3] = Oacc[dt][3] * inv;
      *(f32x4*)(op + 16*dt + 4*lg) = ov;
    }
  }
#undef STAGE_ISSUE
#undef STAGE_REG
#undef STAGE_WRITE
#undef COMPUTE
#undef SEAM
#undef PITER
}

extern "C" void kernel_launch(void* const* d_in, const int* in_sizes, int n_in,
                              void* d_out, int out_size, void* d_ws, size_t ws_size,
                              hipStream_t stream)
{
  const float* Q  = nullptr;
  const float* KV = nullptr;
  const int*   M  = nullptr;
  for (int i = 0; i < n_in; ++i){
    if      (in_sizes[i] == 4194304) Q  = (const float*)d_in[i];
    else if (in_sizes[i] == 8388608) KV = (const float*)d_in[i];
    else if (in_sizes[i] == 4096)    M  = (const int*)d_in[i];
  }
  if (!Q)  Q  = (const float*)d_in[0];
  if (!KV) KV = (const float*)d_in[1];
  if (!M)  M  = (const int*)d_in[2];
  float* O = (float*)d_out;

  const size_t NEED = 16384ull + 1024ull*16384ull;   // biasM + KV image (16.8 MB)
  if (ws_size >= NEED){
    float* biasm = (float*)d_ws;
    u16*   img   = (u16*)((char*)d_ws + 16384);
    prepass<<<dim3(1024), dim3(256), 0, stream>>>(KV, M, img, biasm);
    attn_main<1><<<dim3(512), dim3(512), 0, stream>>>(Q, KV, M, img, biasm, O);
  } else {
    attn_main<0><<<dim3(512), dim3(512), 0, stream>>>(Q, KV, M, nullptr, nullptr, O);
  }
}

// Round 15
// 66.433 us; speedup vs baseline: 1.0432x; 1.0432x over previous
//
#include <hip/hip_runtime.h>

typedef unsigned short u16;
typedef unsigned int   u32;
typedef u16   u16x8 __attribute__((ext_vector_type(8)));
typedef float f32x4 __attribute__((ext_vector_type(4)));
typedef __bf16 bf16x8 __attribute__((ext_vector_type(8)));
typedef u32   u32x2 __attribute__((ext_vector_type(2)));
typedef u32   u32x4 __attribute__((ext_vector_type(4)));

#define QSCALE  0.18033688011112f     // 0.125 * log2(e): scores in exp2 units
#define BM_OPEN  -28.8539008177793f   // -20 * log2(e)
#define BM_MASK  -14455.8043097f      // -(10000+20) * log2(e)

__device__ __forceinline__ u16 f2bf(float x){
  __bf16 h = (__bf16)x;
  return __builtin_bit_cast(u16, h);
}
__device__ __forceinline__ f32x4 mfma16x16x32(u16x8 a, u16x8 b, f32x4 c){
  return __builtin_amdgcn_mfma_f32_16x16x32_bf16(
      __builtin_bit_cast(bf16x8, a), __builtin_bit_cast(bf16x8, b), c, 0, 0, 0);
}
__device__ __forceinline__ void gld16(const void* g, void* l){
  __builtin_amdgcn_global_load_lds(
      (const __attribute__((address_space(1))) u32*)g,
      (__attribute__((address_space(3))) u32*)l, 16, 0, 0);
}

// ===================== layout =====================
// Per (b,h,kt) tile: 8192 u16 = [K 4096 | V 4096], 16384 B.
//  K: K[key][d] bf16. Row=key, stride 64 u16 (128 B). chunk c at c ^ (key&7).
//  V: V^T[d][s] u32 (s,s+1)-pairs. Row=d, 32 u32. chunk c at c ^ (d&7).

// ===================== pre-pass: f32 KV -> swizzled bf16 tile image ==========
__global__ __launch_bounds__(256, 4)
void prepass(const float* __restrict__ KV, const int* __restrict__ MASK,
             u16* __restrict__ IMG, float* __restrict__ BIASM)
{
  const int tid = threadIdx.x;
  const int bid = blockIdx.x;        // ((b*16+h)*32 + kt)
  const int kt = bid & 31;
  const int h  = (bid >> 5) & 15;
  const int b  = bid >> 9;
  const int kb = kt*64;
  const size_t kv_b = (size_t)b*(2048u*2048u);
  u16* tile = IMG + (size_t)bid * 8192;

  {
    const int skey = tid >> 2, scp = tid & 3;
    const float* kp = KV + kv_b + (size_t)(kb + skey)*2048 + h*64 + 16*scp;
    f32x4 f0 = *(const f32x4*)(kp);
    f32x4 f1 = *(const f32x4*)(kp + 4);
    f32x4 f2 = *(const f32x4*)(kp + 8);
    f32x4 f3 = *(const f32x4*)(kp + 12);
    u16x8 c0, c1;
    #pragma unroll
    for (int e = 0; e < 4; ++e){
      c0[e] = f2bf(f0[e]); c0[e+4] = f2bf(f1[e]);
      c1[e] = f2bf(f2[e]); c1[e+4] = f2bf(f3[e]);
    }
    const int idx0 = skey*64 + (((2*scp) ^ (skey & 7)) << 3);
    *(u16x8*)&tile[idx0]     = c0;
    *(u16x8*)&tile[idx0 ^ 8] = c1;
  }
  {
    const int sdb = tid & 7, ssp = tid >> 3;
    const float* vp = KV + kv_b + (size_t)(kb + 2*ssp)*2048 + 1024 + h*64 + 8*sdb;
    f32x4 r0a = *(const f32x4*)(vp);
    f32x4 r0b = *(const f32x4*)(vp + 4);
    f32x4 r1a = *(const f32x4*)(vp + 2048);
    f32x4 r1b = *(const f32x4*)(vp + 2048 + 4);
    u32* vimg = (u32*)(tile + 4096);
    const int wc = ssp >> 2, wi = ssp & 3;
    #pragma unroll
    for (int j = 0; j < 4; ++j){
      const int d0 = 8*sdb + j;
      const int d1 = d0 + 4;
      vimg[d0*32 + ((wc ^ (d0 & 7)) << 2) + wi] = (u32)f2bf(r0a[j]) | ((u32)f2bf(r1a[j]) << 16);
      vimg[d1*32 + ((wc ^ (d1 & 7)) << 2) + wi] = (u32)f2bf(r0b[j]) | ((u32)f2bf(r1b[j]) << 16);
    }
  }
  if (h == 0 && tid < 64){
    const int s = kb + tid;
    BIASM[b*2048 + s] = MASK[b*2048 + s] ? BM_OPEN : BM_MASK;
  }
}

// ===================== main: MFMA flash attention, fixed-shift softmax =======
// Grid 512. Block = 4 waves x 32 q-rows = 128 rows (256 threads).
// PRE=1: triple-buffered DMA depth-2; bias staged to LDS once (NO per-tile
//        VMEM in the loop -> counted vmcnt seams actually keep DMA in flight).
// PRE=0: fallback, double-buffered reg staging with __syncthreads.
template<int PRE>
__global__ __launch_bounds__(256, 2)
void attn_main(const float* __restrict__ Q, const float* __restrict__ KV,
               const int* __restrict__ MASK, const u16* __restrict__ IMG,
               const float* __restrict__ BIASM, float* __restrict__ OUT)
{
  __shared__ __align__(16) u16 KVbuf[3][8192];   // 48 KB (PRE=0 uses [0],[1])
  __shared__ __align__(16) u32 Pw[4][32*36];     // per-wave P, stride-36 (18 KB)
  __shared__ __align__(16) float BiasLds[2048];  // this block's b-row (8 KB)

  const int tid  = threadIdx.x;
  const int w    = tid >> 6;
  const int lane = tid & 63;
  const int lg   = lane >> 4;
  const int ln   = lane & 15;

  const int bid0 = blockIdx.x;
  const int bid  = (bid0 & 7)*64 + (bid0 >> 3);   // XCD swizzle (bijective 8x64)
  const int qt  = bid & 15;
  const int h   = (bid >> 4) & 15;
  const int b   = bid >> 8;

  const int qbase = qt*128 + w*32;
  const size_t q_b  = (size_t)b * (2048u*1024u);
  const size_t kv_b = (size_t)b * (2048u*2048u);

  const int lnoff = ln*64;
  const int ck0   = ((lg ^ (ln & 7)) << 3);
  const int ck1   = ck0 ^ 32;

  // ---- Q fragments ----
  u16x8 Qf[2][2];
  #pragma unroll
  for (int G = 0; G < 2; ++G){
    const int qrow = qbase + 16*G + ln;
    const float* qp = Q + q_b + (size_t)qrow*1024 + h*64 + 8*lg;
    #pragma unroll
    for (int kc = 0; kc < 2; ++kc){
      f32x4 a = *(const f32x4*)(qp + 32*kc);
      f32x4 c = *(const f32x4*)(qp + 32*kc + 4);
      u16x8 v;
      #pragma unroll
      for (int e = 0; e < 4; ++e){
        v[e]     = f2bf(a[e] * QSCALE);
        v[e + 4] = f2bf(c[e] * QSCALE);
      }
      Qf[G][kc] = v;
    }
  }

  f32x4 Oacc[2][4];
  #pragma unroll
  for (int G = 0; G < 2; ++G)
    #pragma unroll
    for (int dt = 0; dt < 4; ++dt)
      Oacc[G][dt] = f32x4{0.f,0.f,0.f,0.f};
  float lrun[2] = { 0.f, 0.f };

  // staging constants
  const char* img0 = (const char*)IMG + (size_t)((b*16 + h)*32) * 16384;
  const int so = tid*16;
  const int skey = tid >> 2, scp = tid & 3;   // PRE=0 K
  const int sdb  = tid & 7,  ssp = tid >> 3;  // PRE=0 V
  const float* kp0 = KV + kv_b + (size_t)skey*2048 + h*64 + 16*scp;
  const float* vp0 = KV + kv_b + (size_t)(2*ssp)*2048 + 1024 + h*64 + 8*sdb;
  f32x4 kf0, kf1, kf2, kf3, va, vb2, vc, vd;   // PRE=0 staging regs

#define STAGE_ISSUE(T, DST) do{                                               \
    const char* g_ = img0 + (size_t)(T)*16384;                                \
    char* l_ = (char*)(DST);                                                  \
    gld16(g_+so,        l_+so);                                               \
    gld16(g_+so+4096,   l_+so+4096);                                          \
    gld16(g_+so+8192,   l_+so+8192);                                          \
    gld16(g_+so+12288,  l_+so+12288);                                         \
  }while(0)

// bias row (8 KB) -> LDS once; issued BEFORE tile-0 DMA so prologue seam covers it
#define BIAS_STAGE() do{                                                      \
    const char* gb_ = (const char*)BIASM + (size_t)b*8192;                    \
    char* lb_ = (char*)BiasLds;                                               \
    gld16(gb_+so,      lb_+so);                                               \
    gld16(gb_+so+4096, lb_+so+4096);                                          \
  }while(0)

#define STAGE_REG(T) do{                                                      \
    const float* kp_ = kp0 + (size_t)(T)*64*2048;                             \
    kf0=*(const f32x4*)(kp_);   kf1=*(const f32x4*)(kp_+4);                   \
    kf2=*(const f32x4*)(kp_+8); kf3=*(const f32x4*)(kp_+12);                  \
    const float* vp_ = vp0 + (size_t)(T)*64*2048;                             \
    va=*(const f32x4*)(vp_);      vb2=*(const f32x4*)(vp_+4);                 \
    vc=*(const f32x4*)(vp_+2048); vd =*(const f32x4*)(vp_+2048+4);            \
  }while(0)

#define STAGE_WRITE(DST) do{                                                  \
    u16x8 c0_, c1_;                                                           \
    _Pragma("unroll") for (int e_=0; e_<4; ++e_){                             \
      c0_[e_]=f2bf(kf0[e_]); c0_[e_+4]=f2bf(kf1[e_]);                         \
      c1_[e_]=f2bf(kf2[e_]); c1_[e_+4]=f2bf(kf3[e_]); }                       \
    const int kix_ = skey*64 + (((2*scp) ^ (skey & 7)) << 3);                 \
    *(u16x8*)&(DST)[kix_]     = c0_;                                          \
    *(u16x8*)&(DST)[kix_ ^ 8] = c1_;                                          \
    u32* vimg_ = (u32*)((DST)+4096);                                          \
    const int wc_ = ssp >> 2, wi_ = ssp & 3;                                  \
    _Pragma("unroll") for (int j_=0; j_<4; ++j_){                             \
      const int d0_=8*sdb+j_, d1_=d0_+4;                                      \
      vimg_[d0_*32 + ((wc_ ^ (d0_&7)) << 2) + wi_] = (u32)f2bf(va[j_])  | ((u32)f2bf(vc[j_])<<16); \
      vimg_[d1_*32 + ((wc_ ^ (d1_&7)) << 2) + wi_] = (u32)f2bf(vb2[j_]) | ((u32)f2bf(vd[j_])<<16); \
    }                                                                         \
  }while(0)

#define COMPUTE(T, CUR) do{                                                   \
    const u16* Kb_ = (CUR);                                                   \
    const u16* Vb_ = (CUR) + 4096;                                            \
    f32x4 S[2][4];                                                            \
    _Pragma("unroll") for (int ct = 0; ct < 4; ++ct){                         \
      f32x4 bv;                                                               \
      if constexpr (PRE){                                                     \
        bv = *(const f32x4*)&BiasLds[(T)*64 + 16*ct + 4*lg];                  \
      } else {                                                                \
        const int4 mv = *(const int4*)(MASK + b*2048 + (T)*64 + 16*ct + 4*lg);\
        bv[0] = mv.x ? BM_OPEN : BM_MASK;                                     \
        bv[1] = mv.y ? BM_OPEN : BM_MASK;                                     \
        bv[2] = mv.z ? BM_OPEN : BM_MASK;                                     \
        bv[3] = mv.w ? BM_OPEN : BM_MASK;                                     \
      }                                                                       \
      S[0][ct] = bv;                                                          \
      S[1][ct] = bv;                                                          \
    }                                                                         \
    __builtin_amdgcn_s_setprio(1);                                            \
    _Pragma("unroll") for (int ct = 0; ct < 4; ++ct){                         \
      const int rb = ct*1024 + lnoff;                                         \
      u16x8 k0 = *(const u16x8*)&Kb_[rb + ck0];                               \
      u16x8 k1 = *(const u16x8*)&Kb_[rb + ck1];                               \
      S[0][ct] = mfma16x16x32(k0, Qf[0][0], S[0][ct]);                        \
      S[1][ct] = mfma16x16x32(k0, Qf[1][0], S[1][ct]);                        \
      S[0][ct] = mfma16x16x32(k1, Qf[0][1], S[0][ct]);                        \
      S[1][ct] = mfma16x16x32(k1, Qf[1][1], S[1][ct]);                        \
    }                                                                         \
    __builtin_amdgcn_s_setprio(0);                                            \
    _Pragma("unroll") for (int G = 0; G < 2; ++G){                            \
      float ps = 0.f;                                                         \
      _Pragma("unroll") for (int ct = 0; ct < 4; ++ct){                       \
        _Pragma("unroll") for (int r = 0; r < 4; ++r){                        \
          const float p = __builtin_amdgcn_exp2f(S[G][ct][r]);                \
          S[G][ct][r] = p;                                                    \
          ps += p;                                                            \
        }                                                                     \
      }                                                                       \
      lrun[G] += ps;                                                          \
      _Pragma("unroll") for (int ct = 0; ct < 4; ++ct){                       \
        u32x2 pw;                                                             \
        pw[0] = (u32)f2bf(S[G][ct][0]) | ((u32)f2bf(S[G][ct][1]) << 16);      \
        pw[1] = (u32)f2bf(S[G][ct][2]) | ((u32)f2bf(S[G][ct][3]) << 16);      \
        *(u32x2*)&Pw[w][(16*G + ln)*36 + 8*ct + 2*lg] = pw;                   \
      }                                                                       \
    }                                                                         \
    asm volatile("" ::: "memory");                                            \
    u16x8 Pf[2][2];                                                           \
    _Pragma("unroll") for (int G = 0; G < 2; ++G)                             \
      _Pragma("unroll") for (int sc = 0; sc < 2; ++sc){                       \
        u32x4 pr = *(const u32x4*)&Pw[w][(16*G + ln)*36 + 4*lg + 16*sc];      \
        Pf[G][sc] = __builtin_bit_cast(u16x8, pr);                            \
      }                                                                       \
    __builtin_amdgcn_s_setprio(1);                                            \
    _Pragma("unroll") for (int dt = 0; dt < 4; ++dt){                         \
      const int rb = dt*1024 + lnoff;                                         \
      u16x8 v0 = *(const u16x8*)&Vb_[rb + ck0];                               \
      u16x8 v1 = *(const u16x8*)&Vb_[rb + ck1];                               \
      Oacc[0][dt] = mfma16x16x32(v0, Pf[0][0], Oacc[0][dt]);                  \
      Oacc[1][dt] = mfma16x16x32(v0, Pf[1][0], Oacc[1][dt]);                  \
      Oacc[0][dt] = mfma16x16x32(v1, Pf[0][1], Oacc[0][dt]);                  \
      Oacc[1][dt] = mfma16x16x32(v1, Pf[1][1], Oacc[1][dt]);                  \
    }                                                                         \
    __builtin_amdgcn_s_setprio(0);                                            \
  }while(0)

#define SEAM(N) do{                                                           \
    __builtin_amdgcn_sched_barrier(0);                                        \
    asm volatile("s_waitcnt vmcnt(%0)" :: "i"(N) : "memory");                 \
    __builtin_amdgcn_sched_barrier(0);                                        \
    __builtin_amdgcn_s_barrier();                                             \
  }while(0)

#define PITER(T, CUR, FREE) do{                                               \
    if ((T) + 2 <= 31) STAGE_ISSUE((T)+2, FREE);                              \
    COMPUTE(T, CUR);                                                          \
    SEAM(4);                                                                  \
  }while(0)

  if constexpr (PRE){
    u16* b0 = &KVbuf[0][0];
    u16* b1 = &KVbuf[1][0];
    u16* b2 = &KVbuf[2][0];
    // prologue: bias (oldest) + tiles 0,1 in flight; SEAM(4) completes
    // bias(2)+tile0(4), leaves tile1's 4 loads in flight.
    BIAS_STAGE();
    STAGE_ISSUE(0, b0);
    STAGE_ISSUE(1, b1);
    SEAM(4);
    for (int u = 0; u < 10; ++u){
      PITER(3*u    , b0, b2);
      PITER(3*u + 1, b1, b0);
      PITER(3*u + 2, b2, b1);
    }
    COMPUTE(30, b0);
    SEAM(0);
    COMPUTE(31, b1);
  } else {
    STAGE_REG(0);
    STAGE_WRITE(&KVbuf[0][0]);
    __syncthreads();
    for (int t = 0; t < 32; ++t){
      if (t < 31) STAGE_REG(t+1);
      COMPUTE(t, &KVbuf[t & 1][0]);
      if (t < 31){
        STAGE_WRITE(&KVbuf[(t+1) & 1][0]);
        __syncthreads();
      }
    }
  }

  // ---- epilogue: reduce partial l, normalize, store f32 ----
  #pragma unroll
  for (int G = 0; G < 2; ++G){
    float l_ = lrun[G];
    l_ += __shfl_xor(l_, 16, 64);
    l_ += __shfl_xor(l_, 32, 64);
    const float inv = 1.f / l_;
    const int qrow = qbase + 16*G + ln;
    float* op = OUT + q_b + (size_t)qrow*1024 + h*64;
    #pragma unroll
    for (int dt = 0; dt < 4; ++dt){
      f32x4 ov;
      ov[0] = Oacc[G][dt][0] * inv;
      ov[1] = Oacc[G][dt][1] * inv;
      ov[2] = Oacc[G][dt][2] * inv;
      ov[3] = Oacc[G][dt][3] * inv;
      *(f32x4*)(op + 16*dt + 4*lg) = ov;
    }
  }
#undef STAGE_ISSUE
#undef BIAS_STAGE
#undef STAGE_REG
#undef STAGE_WRITE
#undef COMPUTE
#undef SEAM
#undef PITER
}

extern "C" void kernel_launch(void* const* d_in, const int* in_sizes, int n_in,
                              void* d_out, int out_size, void* d_ws, size_t ws_size,
                              hipStream_t stream)
{
  const float* Q  = nullptr;
  const float* KV = nullptr;
  const int*   M  = nullptr;
  for (int i = 0; i < n_in; ++i){
    if      (in_sizes[i] == 4194304) Q  = (const float*)d_in[i];
    else if (in_sizes[i] == 8388608) KV = (const float*)d_in[i];
    else if (in_sizes[i] == 4096)    M  = (const int*)d_in[i];
  }
  if (!Q)  Q  = (const float*)d_in[0];
  if (!KV) KV = (const float*)d_in[1];
  if (!M)  M  = (const int*)d_in[2];
  float* O = (float*)d_out;

  const size_t NEED = 16384ull + 1024ull*16384ull;   // biasM + KV image (16.8 MB)
  if (ws_size >= NEED){
    float* biasm = (float*)d_ws;
    u16*   img   = (u16*)((char*)d_ws + 16384);
    prepass<<<dim3(1024), dim3(256), 0, stream>>>(KV, M, img, biasm);
    attn_main<1><<<dim3(512), dim3(256), 0, stream>>>(Q, KV, M, img, biasm, O);
  } else {
    attn_main<0><<<dim3(512), dim3(256), 0, stream>>>(Q, KV, M, nullptr, nullptr, O);
  }
}

// Round 16
// 59.915 us; speedup vs baseline: 1.1567x; 1.1088x over previous
//
#include <hip/hip_runtime.h>

typedef unsigned short u16;
typedef unsigned int   u32;
typedef u16   u16x8 __attribute__((ext_vector_type(8)));
typedef float f32x4 __attribute__((ext_vector_type(4)));
typedef float f32x16 __attribute__((ext_vector_type(16)));
typedef __bf16 bf16x8 __attribute__((ext_vector_type(8)));
typedef u32   u32x4 __attribute__((ext_vector_type(4)));

#define QSCALE  0.18033688011112f     // 0.125 * log2(e): scores in exp2 units
#define BM_OPEN  -28.8539008177793f   // -20 * log2(e)
#define BM_MASK  -14455.8043097f      // -(10000+20) * log2(e)

__device__ __forceinline__ u16 f2bf(float x){
  __bf16 h = (__bf16)x;
  return __builtin_bit_cast(u16, h);
}
__device__ __forceinline__ f32x16 mfma32(u16x8 a, u16x8 b, f32x16 c){
  return __builtin_amdgcn_mfma_f32_32x32x16_bf16(
      __builtin_bit_cast(bf16x8, a), __builtin_bit_cast(bf16x8, b), c, 0, 0, 0);
}
__device__ __forceinline__ void gld16(const void* g, void* l){
  __builtin_amdgcn_global_load_lds(
      (const __attribute__((address_space(1))) u32*)g,
      (__attribute__((address_space(3))) u32*)l, 16, 0, 0);
}
__device__ __forceinline__ u32 cvtpk(float lo, float hi){
  u32 d;
  asm("v_cvt_pk_bf16_f32 %0, %1, %2" : "=v"(d) : "v"(lo), "v"(hi));
  return d;
}
// v_permlane32_swap_b32: x' = [x lo32 | y lo32], y' = [x hi32 | y hi32]
__device__ __forceinline__ void plswap(u32 &x, u32 &y){
  asm("v_permlane32_swap_b32 %0, %1" : "+v"(x), "+v"(y));
}

// ===================== layout (unchanged image) =====================
// Per (b,h,kt) tile: 8192 u16 = [K 4096 | V 4096], 16384 B.
//  K: K[key][d] bf16. Row=key, stride 64 u16 (128 B). chunk c at c ^ (key&7).
//  V: V^T[d][s] u32 (s,s+1)-pairs. Row=d, 32 u32. chunk c at c ^ (d&7).

// ===================== pre-pass: f32 KV -> swizzled bf16 tile image ==========
__global__ __launch_bounds__(256, 4)
void prepass(const float* __restrict__ KV, const int* __restrict__ MASK,
             u16* __restrict__ IMG, float* __restrict__ BIASM)
{
  const int tid = threadIdx.x;
  const int bid = blockIdx.x;        // ((b*16+h)*32 + kt)
  const int kt = bid & 31;
  const int h  = (bid >> 5) & 15;
  const int b  = bid >> 9;
  const int kb = kt*64;
  const size_t kv_b = (size_t)b*(2048u*2048u);
  u16* tile = IMG + (size_t)bid * 8192;

  {
    const int skey = tid >> 2, scp = tid & 3;
    const float* kp = KV + kv_b + (size_t)(kb + skey)*2048 + h*64 + 16*scp;
    f32x4 f0 = *(const f32x4*)(kp);
    f32x4 f1 = *(const f32x4*)(kp + 4);
    f32x4 f2 = *(const f32x4*)(kp + 8);
    f32x4 f3 = *(const f32x4*)(kp + 12);
    u16x8 c0, c1;
    #pragma unroll
    for (int e = 0; e < 4; ++e){
      c0[e] = f2bf(f0[e]); c0[e+4] = f2bf(f1[e]);
      c1[e] = f2bf(f2[e]); c1[e+4] = f2bf(f3[e]);
    }
    const int idx0 = skey*64 + (((2*scp) ^ (skey & 7)) << 3);
    *(u16x8*)&tile[idx0]     = c0;
    *(u16x8*)&tile[idx0 ^ 8] = c1;
  }
  {
    const int sdb = tid & 7, ssp = tid >> 3;
    const float* vp = KV + kv_b + (size_t)(kb + 2*ssp)*2048 + 1024 + h*64 + 8*sdb;
    f32x4 r0a = *(const f32x4*)(vp);
    f32x4 r0b = *(const f32x4*)(vp + 4);
    f32x4 r1a = *(const f32x4*)(vp + 2048);
    f32x4 r1b = *(const f32x4*)(vp + 2048 + 4);
    u32* vimg = (u32*)(tile + 4096);
    const int wc = ssp >> 2, wi = ssp & 3;
    #pragma unroll
    for (int j = 0; j < 4; ++j){
      const int d0 = 8*sdb + j;
      const int d1 = d0 + 4;
      vimg[d0*32 + ((wc ^ (d0 & 7)) << 2) + wi] = (u32)f2bf(r0a[j]) | ((u32)f2bf(r1a[j]) << 16);
      vimg[d1*32 + ((wc ^ (d1 & 7)) << 2) + wi] = (u32)f2bf(r0b[j]) | ((u32)f2bf(r1b[j]) << 16);
    }
  }
  if (h == 0 && tid < 64){
    const int s = kb + tid;
    BIASM[b*2048 + s] = MASK[b*2048 + s] ? BM_OPEN : BM_MASK;
  }
}

// ===================== main: 32x32 MFMA flash attention ======================
// Grid 512. Block = 4 waves x 32 q-rows = 128 rows (256 threads).
// 32x32x16 MFMA; P stays in registers (cvt_pk + permlane32_swap) — NO P LDS.
// PRE=1: triple-buffered DMA depth-2, bias in LDS, counted vmcnt seams.
template<int PRE>
__global__ __launch_bounds__(256, 2)
void attn_main(const float* __restrict__ Q, const float* __restrict__ KV,
               const int* __restrict__ MASK, const u16* __restrict__ IMG,
               const float* __restrict__ BIASM, float* __restrict__ OUT)
{
  __shared__ __align__(16) u16 KVbuf[3][8192];   // 48 KB (PRE=0 uses [0],[1])
  __shared__ __align__(16) float BiasLds[2048];  // this block's b-row (8 KB)

  const int tid  = threadIdx.x;
  const int w    = tid >> 6;
  const int lane = tid & 63;
  const int hi   = lane >> 5;     // lane half
  const int lq   = lane & 31;     // q (and A-row) index

  const int bid0 = blockIdx.x;
  const int bid  = (bid0 & 7)*64 + (bid0 >> 3);   // XCD swizzle (bijective 8x64)
  const int qt  = bid & 15;
  const int h   = (bid >> 4) & 15;
  const int b   = bid >> 8;

  const int qbase = qt*128 + w*32;
  const size_t q_b  = (size_t)b * (2048u*1024u);
  const size_t kv_b = (size_t)b * (2048u*2048u);

  const int sw7 = lq & 7;         // row&7 for both K (row=32ct+lq) and V (row=32dt+lq)

  // ---- Q fragments: B-frag for 32x32x16, lane holds Q[q=lq][d=16kc+8hi+e] ----
  u16x8 Qf[4];
  {
    const int qrow = qbase + lq;
    const float* qp = Q + q_b + (size_t)qrow*1024 + h*64 + 8*hi;
    #pragma unroll
    for (int kc = 0; kc < 4; ++kc){
      f32x4 a = *(const f32x4*)(qp + 16*kc);
      f32x4 c = *(const f32x4*)(qp + 16*kc + 4);
      u16x8 v;
      #pragma unroll
      for (int e = 0; e < 4; ++e){
        v[e]     = f2bf(a[e] * QSCALE);
        v[e + 4] = f2bf(c[e] * QSCALE);
      }
      Qf[kc] = v;
    }
  }

  f32x16 Oa[2];
  #pragma unroll
  for (int dt = 0; dt < 2; ++dt)
    #pragma unroll
    for (int r = 0; r < 16; ++r) Oa[dt][r] = 0.f;
  float lrun = 0.f;

  // staging constants (image layout unchanged)
  const char* img0 = (const char*)IMG + (size_t)((b*16 + h)*32) * 16384;
  const int so = tid*16;
  const int skey = tid >> 2, scp = tid & 3;   // PRE=0 K
  const int sdb  = tid & 7,  ssp = tid >> 3;  // PRE=0 V
  const float* kp0 = KV + kv_b + (size_t)skey*2048 + h*64 + 16*scp;
  const float* vp0 = KV + kv_b + (size_t)(2*ssp)*2048 + 1024 + h*64 + 8*sdb;
  f32x4 kf0, kf1, kf2, kf3, va, vb2, vc, vd;   // PRE=0 staging regs

#define STAGE_ISSUE(T, DST) do{                                               \
    const char* g_ = img0 + (size_t)(T)*16384;                                \
    char* l_ = (char*)(DST);                                                  \
    gld16(g_+so,        l_+so);                                               \
    gld16(g_+so+4096,   l_+so+4096);                                          \
    gld16(g_+so+8192,   l_+so+8192);                                          \
    gld16(g_+so+12288,  l_+so+12288);                                         \
  }while(0)

#define BIAS_STAGE() do{                                                      \
    const char* gb_ = (const char*)BIASM + (size_t)b*8192;                    \
    char* lb_ = (char*)BiasLds;                                               \
    gld16(gb_+so,      lb_+so);                                               \
    gld16(gb_+so+4096, lb_+so+4096);                                          \
  }while(0)

#define STAGE_REG(T) do{                                                      \
    const float* kp_ = kp0 + (size_t)(T)*64*2048;                             \
    kf0=*(const f32x4*)(kp_);   kf1=*(const f32x4*)(kp_+4);                   \
    kf2=*(const f32x4*)(kp_+8); kf3=*(const f32x4*)(kp_+12);                  \
    const float* vp_ = vp0 + (size_t)(T)*64*2048;                             \
    va=*(const f32x4*)(vp_);      vb2=*(const f32x4*)(vp_+4);                 \
    vc=*(const f32x4*)(vp_+2048); vd =*(const f32x4*)(vp_+2048+4);            \
  }while(0)

#define STAGE_WRITE(DST) do{                                                  \
    u16x8 c0_, c1_;                                                           \
    _Pragma("unroll") for (int e_=0; e_<4; ++e_){                             \
      c0_[e_]=f2bf(kf0[e_]); c0_[e_+4]=f2bf(kf1[e_]);                         \
      c1_[e_]=f2bf(kf2[e_]); c1_[e_+4]=f2bf(kf3[e_]); }                       \
    const int kix_ = skey*64 + (((2*scp) ^ (skey & 7)) << 3);                 \
    *(u16x8*)&(DST)[kix_]     = c0_;                                          \
    *(u16x8*)&(DST)[kix_ ^ 8] = c1_;                                          \
    u32* vimg_ = (u32*)((DST)+4096);                                          \
    const int wc_ = ssp >> 2, wi_ = ssp & 3;                                  \
    _Pragma("unroll") for (int j_=0; j_<4; ++j_){                             \
      const int d0_=8*sdb+j_, d1_=d0_+4;                                      \
      vimg_[d0_*32 + ((wc_ ^ (d0_&7)) << 2) + wi_] = (u32)f2bf(va[j_])  | ((u32)f2bf(vc[j_])<<16); \
      vimg_[d1_*32 + ((wc_ ^ (d1_&7)) << 2) + wi_] = (u32)f2bf(vb2[j_]) | ((u32)f2bf(vd[j_])<<16); \
    }                                                                         \
  }while(0)

// COMPUTE: S C-init from bias; QK (8 MFMA); exp2; cvt_pk+permlane -> P frags;
// PV (8 MFMA). Zero LDS writes; K/V/bias reads only.
#define COMPUTE(T, CUR) do{                                                   \
    const u16* Kb_ = (CUR);                                                   \
    const u32* vimg_ = (const u32*)((CUR) + 4096);                            \
    f32x16 S[2];                                                              \
    _Pragma("unroll") for (int ct = 0; ct < 2; ++ct){                         \
      _Pragma("unroll") for (int m = 0; m < 4; ++m){                          \
        f32x4 bq;                                                             \
        if constexpr (PRE){                                                   \
          bq = *(const f32x4*)&BiasLds[(T)*64 + 32*ct + 8*m + 4*hi];          \
        } else {                                                              \
          const int4 mv = *(const int4*)(MASK + b*2048 + (T)*64 + 32*ct + 8*m + 4*hi); \
          bq[0] = mv.x ? BM_OPEN : BM_MASK;                                   \
          bq[1] = mv.y ? BM_OPEN : BM_MASK;                                   \
          bq[2] = mv.z ? BM_OPEN : BM_MASK;                                   \
          bq[3] = mv.w ? BM_OPEN : BM_MASK;                                   \
        }                                                                     \
        S[ct][4*m+0] = bq[0]; S[ct][4*m+1] = bq[1];                           \
        S[ct][4*m+2] = bq[2]; S[ct][4*m+3] = bq[3];                           \
      }                                                                       \
    }                                                                         \
    __builtin_amdgcn_s_setprio(1);                                            \
    _Pragma("unroll") for (int ct = 0; ct < 2; ++ct){                         \
      _Pragma("unroll") for (int kc = 0; kc < 4; ++kc){                       \
        u16x8 kf = *(const u16x8*)&Kb_[(32*ct + lq)*64 + (((2*kc + hi) ^ sw7) << 3)]; \
        S[ct] = mfma32(kf, Qf[kc], S[ct]);                                    \
      }                                                                       \
    }                                                                         \
    __builtin_amdgcn_s_setprio(0);                                            \
    u32 pa[2][4], pb[2][4];                                                   \
    float ps = 0.f;                                                           \
    _Pragma("unroll") for (int ct = 0; ct < 2; ++ct){                         \
      _Pragma("unroll") for (int m = 0; m < 4; ++m){                          \
        const float p0 = __builtin_amdgcn_exp2f(S[ct][4*m+0]);                \
        const float p1 = __builtin_amdgcn_exp2f(S[ct][4*m+1]);                \
        const float p2 = __builtin_amdgcn_exp2f(S[ct][4*m+2]);                \
        const float p3 = __builtin_amdgcn_exp2f(S[ct][4*m+3]);                \
        ps += (p0 + p1) + (p2 + p3);                                          \
        pa[ct][m] = cvtpk(p0, p1);                                            \
        pb[ct][m] = cvtpk(p2, p3);                                            \
      }                                                                       \
    }                                                                         \
    lrun += ps;                                                               \
    /* assemble PV B-frags: frag[sc] holds P[s=16sc+8hi+e][q=lq] */           \
    u16x8 Pf[4];                                                              \
    _Pragma("unroll") for (int ct = 0; ct < 2; ++ct){                         \
      plswap(pa[ct][0], pa[ct][1]);  plswap(pb[ct][0], pb[ct][1]);            \
      plswap(pa[ct][2], pa[ct][3]);  plswap(pb[ct][2], pb[ct][3]);            \
      u32x4 f0_ = { pa[ct][0], pb[ct][0], pa[ct][1], pb[ct][1] };             \
      u32x4 f1_ = { pa[ct][2], pb[ct][2], pa[ct][3], pb[ct][3] };             \
      Pf[2*ct+0] = __builtin_bit_cast(u16x8, f0_);                            \
      Pf[2*ct+1] = __builtin_bit_cast(u16x8, f1_);                            \
    }                                                                         \
    __builtin_amdgcn_s_setprio(1);                                            \
    _Pragma("unroll") for (int dt = 0; dt < 2; ++dt){                         \
      _Pragma("unroll") for (int sc = 0; sc < 4; ++sc){                       \
        u32x4 vv = *(const u32x4*)&vimg_[(32*dt + lq)*32 + (((2*sc + hi) ^ sw7) << 2)]; \
        Oa[dt] = mfma32(__builtin_bit_cast(u16x8, vv), Pf[sc], Oa[dt]);       \
      }                                                                       \
    }                                                                         \
    __builtin_amdgcn_s_setprio(0);                                            \
  }while(0)

#define SEAM(N) do{                                                           \
    __builtin_amdgcn_sched_barrier(0);                                        \
    asm volatile("s_waitcnt vmcnt(%0)" :: "i"(N) : "memory");                 \
    __builtin_amdgcn_sched_barrier(0);                                        \
    __builtin_amdgcn_s_barrier();                                             \
  }while(0)

#define PITER(T, CUR, FREE) do{                                               \
    if ((T) + 2 <= 31) STAGE_ISSUE((T)+2, FREE);                              \
    COMPUTE(T, CUR);                                                          \
    SEAM(4);                                                                  \
  }while(0)

  if constexpr (PRE){
    u16* b0 = &KVbuf[0][0];
    u16* b1 = &KVbuf[1][0];
    u16* b2 = &KVbuf[2][0];
    BIAS_STAGE();                 // bias first (oldest)
    STAGE_ISSUE(0, b0);
    STAGE_ISSUE(1, b1);
    SEAM(4);                      // completes bias(2)+tile0(4); tile1 in flight
    for (int u = 0; u < 10; ++u){
      PITER(3*u    , b0, b2);
      PITER(3*u + 1, b1, b0);
      PITER(3*u + 2, b2, b1);
    }
    COMPUTE(30, b0);
    SEAM(0);
    COMPUTE(31, b1);
  } else {
    STAGE_REG(0);
    STAGE_WRITE(&KVbuf[0][0]);
    __syncthreads();
    for (int t = 0; t < 32; ++t){
      if (t < 31) STAGE_REG(t+1);
      COMPUTE(t, &KVbuf[t & 1][0]);
      if (t < 31){
        STAGE_WRITE(&KVbuf[(t+1) & 1][0]);
        __syncthreads();
      }
    }
  }

  // ---- epilogue: combine lane halves' l, normalize, store f32 ----
  {
    float l_ = lrun + __shfl_xor(lrun, 32, 64);
    const float inv = 1.f / l_;
    const int qrow = qbase + lq;
    float* op = OUT + q_b + (size_t)qrow*1024 + h*64;
    #pragma unroll
    for (int dt = 0; dt < 2; ++dt){
      #pragma unroll
      for (int m = 0; m < 4; ++m){
        f32x4 ov;
        ov[0] = Oa[dt][4*m+0] * inv;
        ov[1] = Oa[dt][4*m+1] * inv;
        ov[2] = Oa[dt][4*m+2] * inv;
        ov[3] = Oa[dt][4*m+3] * inv;
        *(f32x4*)(op + 32*dt + 8*m + 4*hi) = ov;   // d = 32dt+8m+4hi+j
      }
    }
  }
#undef STAGE_ISSUE
#undef BIAS_STAGE
#undef STAGE_REG
#undef STAGE_WRITE
#undef COMPUTE
#undef SEAM
#undef PITER
}

extern "C" void kernel_launch(void* const* d_in, const int* in_sizes, int n_in,
                              void* d_out, int out_size, void* d_ws, size_t ws_size,
                              hipStream_t stream)
{
  const float* Q  = nullptr;
  const float* KV = nullptr;
  const int*   M  = nullptr;
  for (int i = 0; i < n_in; ++i){
    if      (in_sizes[i] == 4194304) Q  = (const float*)d_in[i];
    else if (in_sizes[i] == 8388608) KV = (const float*)d_in[i];
    else if (in_sizes[i] == 4096)    M  = (const int*)d_in[i];
  }
  if (!Q)  Q  = (const float*)d_in[0];
  if (!KV) KV = (const float*)d_in[1];
  if (!M)  M  = (const int*)d_in[2];
  float* O = (float*)d_out;

  const size_t NEED = 16384ull + 1024ull*16384ull;   // biasM + KV image (16.8 MB)
  if (ws_size >= NEED){
    float* biasm = (float*)d_ws;
    u16*   img   = (u16*)((char*)d_ws + 16384);
    prepass<<<dim3(1024), dim3(256), 0, stream>>>(KV, M, img, biasm);
    attn_main<1><<<dim3(512), dim3(256), 0, stream>>>(Q, KV, M, img, biasm, O);
  } else {
    attn_main<0><<<dim3(512), dim3(256), 0, stream>>>(Q, KV, M, nullptr, nullptr, O);
  }
}